// Round 2
// baseline (266.387 us; speedup 1.0000x reference)
//
#include <hip/hip_runtime.h>

#define BB 4
#define NN 16384
#define SS 4096
#define CIN 256
#define COUT 256

#define SC 4                  // s-chunks for knn (1024 candidates/chunk)
#define SCS (SS / SC)         // 1024 points per chunk -> 16 KB LDS
#define KNNB ((NN / 512) * SC * BB)           // 32*4*4 = 512 knn blocks (NPT=2)
#define GEMMB ((COUT / 64) * (SS / 64) * BB)  // 4*64*4 = 1024 gemm blocks
// grid = 1536; knn blocks at bid%3==0 so CU/XCD placement interleaves the
// long knn blocks (~19us) evenly among short gemm blocks (~7us).

typedef float v2f __attribute__((ext_vector_type(2)));
typedef float v4f __attribute__((ext_vector_type(4)));

__device__ __forceinline__ unsigned short f2bf(float f) {   // RNE float->bf16
    unsigned u = __float_as_uint(f);
    u += 0x7FFF + ((u >> 16) & 1);
    return (unsigned short)(u >> 16);
}
__device__ __forceinline__ float bf2f(unsigned short h) {
    return __uint_as_float((unsigned)h << 16);
}

// Packed key: kd = (double)e + 640.0 lies in binade [512,1024) (e in (-78,78)),
// so ulp = 2^-43 fixed; low 12 mantissa bits replaced by s => e quantized at
// 2^-31 absolute (flip prob ~1e-4 total) and ordering == (e, s) lexicographic
// == reference stable top_k tie-break. Insert = select-free min/max network.
__device__ __forceinline__ double pack_key(float e, unsigned gs) {
    double kd = (double)e + 640.0;
    unsigned long long b = __double_as_longlong(kd);
    b = (b & 0xFFFFFFFFFFFFF000ULL) | (unsigned long long)gs;
    return __longlong_as_double((long long)b);
}
__device__ __forceinline__ void insert_key(double& k0, double& k1, double& k2,
                                           double x) {
    double m  = fmax(k0, x);
    k0 = fmin(k0, x);
    double m2 = fmax(k1, m);
    k1 = fmin(k1, m);
    k2 = fmin(k2, m2);
}

// v_pk_fma_f32 packed distance: lo = query A, hi = query B; candidate coords
// broadcast via op_sel. IEEE f32 fma per half, z->y->x order == original fmaf
// nest -> e2 is BITWISE identical to the scalar version (and between phases).
#define E2_FROM(p_xy, p_zw, XX, YY, ZZ, e2)                                    \
    do {                                                                       \
        asm("v_pk_fma_f32 %0, %1, %2, %3 op_sel:[0,0,1] op_sel_hi:[0,1,1]"     \
            : "=v"(e2) : "v"(p_zw), "v"(ZZ), "v"(p_zw));                       \
        asm("v_pk_fma_f32 %0, %1, %2, %0 op_sel:[1,0,0] op_sel_hi:[1,1,1]"     \
            : "+v"(e2) : "v"(p_xy), "v"(YY));                                  \
        asm("v_pk_fma_f32 %0, %1, %2, %0 op_sel:[0,0,0] op_sel_hi:[0,1,1]"     \
            : "+v"(e2) : "v"(p_xy), "v"(XX));                                  \
    } while (0)

#define PK_LO(acc, ap, bw)                                                     \
    asm("v_pk_fma_f32 %0, %1, %2, %0 op_sel:[0,0,0] op_sel_hi:[0,1,1]"         \
        : "+v"(acc) : "v"(ap), "v"(bw))
#define PK_HI(acc, ap, bw)                                                     \
    asm("v_pk_fma_f32 %0, %1, %2, %0 op_sel:[1,0,0] op_sel_hi:[1,1,1]"         \
        : "+v"(acc) : "v"(ap), "v"(bw))

// ---------------------------------------------------------------------------
// knn phase, two passes over the LDS-staged chunk:
//   pass 1: exact f32 top-3 VALUES via 3-op network (min + 2x med3, all
//           reading old state -> full ILP, full-rate f32). No f64, no index.
//   pass 2: recompute e (bit-identical asm); only candidates with e <= m2
//           (third-smallest value) can be in the top-3 -> wave-uniform __any
//           branch guards the exact f64 packed-key insert. The f64 network
//           over this superset yields the identical (e,s)-lex top-3.
// ---------------------------------------------------------------------------
__device__ __forceinline__ void knn_phase(int id, int t, float* smem,
                                          const float* __restrict__ xyz1,
                                          const float* __restrict__ xyz2,
                                          unsigned long long* __restrict__ pk) {
    int nb = id & 31;
    int ch = (id >> 5) & (SC - 1);
    int b  = id >> 7;
    int s0 = ch * SCS;

    float4* smv = (float4*)smem;
    const float* x2 = xyz2 + (size_t)b * 3 * SS;
    for (int i = t; i < SCS; i += 256) {
        float px = x2[s0 + i];
        float py = x2[SS + s0 + i];
        float pz = x2[2 * SS + s0 + i];
        smv[i] = make_float4(px, py, pz, fmaf(px, px, fmaf(py, py, pz * pz)));
    }
    __syncthreads();

    int n0  = nb * 512 + t;
    int n1q = n0 + 256;
    const float* xb = xyz1 + (size_t)b * 3 * NN;
    float ax = xb[n0],  ay = xb[NN + n0],  az = xb[2 * NN + n0];
    float bx = xb[n1q], by = xb[NN + n1q], bz = xb[2 * NN + n1q];
    v2f XX = {-2.0f * ax, -2.0f * bx};
    v2f YY = {-2.0f * ay, -2.0f * by};
    v2f ZZ = {-2.0f * az, -2.0f * bz};

    // ---- pass 1: f32 value-only top-3 screen ----
    float mA0 = 1e30f, mA1 = 1e30f, mA2 = 1e30f;
    float mB0 = 1e30f, mB1 = 1e30f, mB2 = 1e30f;
#pragma unroll 8
    for (int s = 0; s < SCS; ++s) {
        v4f p = *(const v4f*)(smem + 4 * s);
        v2f pxy = __builtin_shufflevector(p, p, 0, 1);
        v2f pzw = __builtin_shufflevector(p, p, 2, 3);
        v2f e2;
        E2_FROM(pxy, pzw, XX, YY, ZZ, e2);
        float nA1 = __builtin_amdgcn_fmed3f(e2.x, mA0, mA1);
        float nA2 = __builtin_amdgcn_fmed3f(e2.x, mA1, mA2);
        mA0 = fminf(mA0, e2.x);
        mA1 = nA1; mA2 = nA2;
        float nB1 = __builtin_amdgcn_fmed3f(e2.y, mB0, mB1);
        float nB2 = __builtin_amdgcn_fmed3f(e2.y, mB1, mB2);
        mB0 = fminf(mB0, e2.y);
        mB1 = nB1; mB2 = nB2;
    }

    // ---- pass 2: filtered exact (e,s)-lex insert ----
    double AK0 = 1023.0, AK1 = 1023.0, AK2 = 1023.0;
    double BK0 = 1023.0, BK1 = 1023.0, BK2 = 1023.0;
#pragma unroll 4
    for (int s = 0; s < SCS; ++s) {
        v4f p = *(const v4f*)(smem + 4 * s);
        v2f pxy = __builtin_shufflevector(p, p, 0, 1);
        v2f pzw = __builtin_shufflevector(p, p, 2, 3);
        v2f e2;
        E2_FROM(pxy, pzw, XX, YY, ZZ, e2);
        bool ca = (e2.x <= mA2);
        bool cb = (e2.y <= mB2);
        if (__any(ca || cb)) {          // wave-uniform skip (P~0.31 taken)
            unsigned gs = (unsigned)(s0 + s);
            if (ca) insert_key(AK0, AK1, AK2, pack_key(e2.x, gs));
            if (cb) insert_key(BK0, BK1, BK2, pack_key(e2.y, gs));
        }
    }

    // layout [ch][b][j][n], u64 keys (coalesced 8B/lane)
    size_t cbk = (size_t)(ch * BB + b) * 3;
    pk[(cbk + 0) * NN + n0]  = (unsigned long long)__double_as_longlong(AK0);
    pk[(cbk + 1) * NN + n0]  = (unsigned long long)__double_as_longlong(AK1);
    pk[(cbk + 2) * NN + n0]  = (unsigned long long)__double_as_longlong(AK2);
    pk[(cbk + 0) * NN + n1q] = (unsigned long long)__double_as_longlong(BK0);
    pk[(cbk + 1) * NN + n1q] = (unsigned long long)__double_as_longlong(BK1);
    pk[(cbk + 2) * NN + n1q] = (unsigned long long)__double_as_longlong(BK2);
}

// ---------------------------------------------------------------------------
// gemm phase: 64s x 64o tile, 4x4 micro via 8 v_pk_fma_f32 per cc.
// ---------------------------------------------------------------------------
__device__ __forceinline__ void gemm_phase(int g, int t, float* smem,
                                           const float* __restrict__ P,
                                           const float* __restrict__ W,
                                           const float* __restrict__ bias,
                                           unsigned short* __restrict__ Gh) {
    int o0 = (g & 3) * 64;
    int s0 = ((g >> 2) & 63) * 64;
    int b  = g >> 8;
    float* sP = smem;              // 16 x 64
    float* sW = smem + 1024;       // 16 x 68 (padded)
    int i = t & 15;
    int j = t >> 4;

    v2f acc2[4][2];
#pragma unroll
    for (int p = 0; p < 4; ++p) {
        acc2[p][0] = (v2f){0.f, 0.f};
        acc2[p][1] = (v2f){0.f, 0.f};
    }

    const float* Pb = P + (size_t)b * CIN * SS;

    for (int c0 = 0; c0 < CIN; c0 += 16) {
        __syncthreads();
        {
            int col = t & 63;
            int r0r = t >> 6;
#pragma unroll
            for (int r = 0; r < 4; ++r) {
                int row = r0r + r * 4;
                sP[row * 64 + col] = Pb[(size_t)(c0 + row) * SS + s0 + col];
            }
        }
        {
            int cc = t & 15;
            int obase = t >> 4;
#pragma unroll
            for (int r = 0; r < 4; ++r) {
                int oo = obase + 16 * r;
                sW[cc * 68 + oo] = W[(size_t)(o0 + oo) * CIN + c0 + cc];
            }
        }
        __syncthreads();

#pragma unroll
        for (int cc = 0; cc < 16; ++cc) {
            v4f a  = *(const v4f*)&sP[cc * 64 + i * 4];
            v4f bv = *(const v4f*)&sW[cc * 68 + j * 4];
            v2f a01 = __builtin_shufflevector(a, a, 0, 1);
            v2f a23 = __builtin_shufflevector(a, a, 2, 3);
            v2f b01 = __builtin_shufflevector(bv, bv, 0, 1);
            v2f b23 = __builtin_shufflevector(bv, bv, 2, 3);
            PK_LO(acc2[0][0], a01, b01); PK_LO(acc2[0][1], a01, b23);  // a.x
            PK_HI(acc2[1][0], a01, b01); PK_HI(acc2[1][1], a01, b23);  // a.y
            PK_LO(acc2[2][0], a23, b01); PK_LO(acc2[2][1], a23, b23);  // a.z
            PK_HI(acc2[3][0], a23, b01); PK_HI(acc2[3][1], a23, b23);  // a.w
        }
    }

    float b0 = bias[o0 + j * 4 + 0];
    float b1 = bias[o0 + j * 4 + 1];
    float b2 = bias[o0 + j * 4 + 2];
    float b3 = bias[o0 + j * 4 + 3];
#pragma unroll
    for (int p = 0; p < 4; ++p) {
        ushort4 v;
        v.x = f2bf(acc2[p][0].x + b0);
        v.y = f2bf(acc2[p][0].y + b1);
        v.z = f2bf(acc2[p][1].x + b2);
        v.w = f2bf(acc2[p][1].y + b3);
        size_t off = ((size_t)b * SS + s0 + i * 4 + p) * COUT + o0 + j * 4;
        *(ushort4*)&Gh[off] = v;
    }
}

// ---------------------------------------------------------------------------
// Split grid (round-1 lesson: per-block fusion cost 2x occupancy, knn is
// latency-sensitive). knn at bid%3==0 interleaves long blocks evenly.
// ---------------------------------------------------------------------------
__global__ __launch_bounds__(256) void k_fused(const float* __restrict__ xyz1,
                                               const float* __restrict__ xyz2,
                                               const float* __restrict__ P,
                                               const float* __restrict__ W,
                                               const float* __restrict__ bias,
                                               unsigned short* __restrict__ Gh,
                                               unsigned long long* __restrict__ pk) {
    __shared__ float smem[4096];   // 16 KB: knn 1024 float4 / gemm sP+sW
    int bid = blockIdx.x;
    int t   = threadIdx.x;

    if (bid % 3 == 0) {
        knn_phase(bid / 3, t, smem, xyz1, xyz2, pk);
    } else {
        gemm_phase(bid - bid / 3 - 1, t, smem, P, W, bias, Gh);
    }
}

// ---------------------------------------------------------------------------
// Merge: fold SC*3 = 12 packed keys per query via the same select-free
// network (order-independent), recompute |p1|^2, decode {d,s} -> wi4/gi4.
// ---------------------------------------------------------------------------
__global__ __launch_bounds__(256) void k_merge(const unsigned long long* __restrict__ pk,
                                               const float* __restrict__ xyz1,
                                               float4* __restrict__ wi4,
                                               int4* __restrict__ gi4) {
    int b = blockIdx.y;
    int n = blockIdx.x * 256 + threadIdx.x;

    double k0 = 1023.0, k1 = 1023.0, k2 = 1023.0;
#pragma unroll
    for (int ch = 0; ch < SC; ++ch) {
        size_t cb = (size_t)(ch * BB + b) * 3;
#pragma unroll
        for (int j = 0; j < 3; ++j) {
            double x = __longlong_as_double(
                (long long)pk[(cb + j) * NN + n]);
            insert_key(k0, k1, k2, x);
        }
    }

    const float* xb = xyz1 + (size_t)b * 3 * NN;
    float qx = xb[n], qy = xb[NN + n], qz = xb[2 * NN + n];
    float n1 = fmaf(qx, qx, fmaf(qy, qy, qz * qz));

    unsigned long long u0 = (unsigned long long)__double_as_longlong(k0);
    unsigned long long u1 = (unsigned long long)__double_as_longlong(k1);
    unsigned long long u2 = (unsigned long long)__double_as_longlong(k2);
    float e0 = (float)(__longlong_as_double((long long)(u0 & ~0xFFFULL)) - 640.0);
    float e1 = (float)(__longlong_as_double((long long)(u1 & ~0xFFFULL)) - 640.0);
    float e2 = (float)(__longlong_as_double((long long)(u2 & ~0xFFFULL)) - 640.0);
    float d0 = e0 + n1, d1 = e1 + n1, d2 = e2 + n1;

    float r0 = 1.0f / (d0 + 1e-8f);
    float r1 = 1.0f / (d1 + 1e-8f);
    float r2 = 1.0f / (d2 + 1e-8f);
    float inv = 1.0f / (r0 + r1 + r2);
    size_t q = (size_t)b * NN + n;
    wi4[q] = make_float4(r0 * inv, r1 * inv, r2 * inv, 0.f);
    gi4[q] = make_int4((int)(u0 & 0xFFFULL), (int)(u1 & 0xFFFULL),
                       (int)(u2 & 0xFFFULL), 0);
}

// ---------------------------------------------------------------------------
// Output: unchanged (XCD-swizzled flat grid, 64q x 64ch blocks,
// 4-query/wave MLP gather, stride-68 tile, coalesced stores).
// ---------------------------------------------------------------------------
__global__ __launch_bounds__(256) void k_out(const unsigned short* __restrict__ Gh,
                                             const float4* __restrict__ wi4,
                                             const int4* __restrict__ gi4,
                                             float* __restrict__ out) {
    __shared__ float  tile[64 * 68];   // 17.4 KB
    __shared__ float4 swv[64];
    __shared__ int4   siv[64];
    int bid  = blockIdx.x;
    int x    = bid & 7;                // XCD slot (blockIdx % 8 round-robin)
    int b    = x >> 1;                 // 2 XCDs per batch
    int local = (bid >> 3) + (x & 1) * 512;   // 0..1023 per batch
    int nb   = local & 255;            // 256 n-blocks
    int oc   = local >> 8;             // 4 o-chunks
    int n0   = nb * 64;
    int o0   = oc * 64;
    int t    = threadIdx.x;
    int wave = t >> 6;
    int lane = t & 63;
    int qg   = lane >> 4;     // query-in-group 0..3
    int c16  = lane & 15;     // channel quad 0..15

    if (t < 64) {
        size_t q = (size_t)b * NN + n0 + t;
        swv[t] = wi4[q];
        siv[t] = gi4[q];
    }
    __syncthreads();

    const unsigned short* Gb = Gh + (size_t)b * SS * COUT;

#pragma unroll
    for (int pass = 0; pass < 4; ++pass) {
        int q = pass * 16 + wave * 4 + qg;
        float4 wv = swv[q];
        int4   iv = siv[q];
        int co = o0 + c16 * 4;
        ushort4 a0 = *(const ushort4*)(Gb + (size_t)iv.x * COUT + co);
        ushort4 a1 = *(const ushort4*)(Gb + (size_t)iv.y * COUT + co);
        ushort4 a2 = *(const ushort4*)(Gb + (size_t)iv.z * COUT + co);
        float4 v;
        v.x = fmaf(wv.x, bf2f(a0.x), fmaf(wv.y, bf2f(a1.x), wv.z * bf2f(a2.x)));
        v.y = fmaf(wv.x, bf2f(a0.y), fmaf(wv.y, bf2f(a1.y), wv.z * bf2f(a2.y)));
        v.z = fmaf(wv.x, bf2f(a0.z), fmaf(wv.y, bf2f(a1.z), wv.z * bf2f(a2.z)));
        v.w = fmaf(wv.x, bf2f(a0.w), fmaf(wv.y, bf2f(a1.w), wv.z * bf2f(a2.w)));
        *(float4*)&tile[q * 68 + c16 * 4] = v;
    }
    __syncthreads();

    float* obase = out + ((size_t)b * COUT + o0) * NN + n0 + lane;
#pragma unroll
    for (int g = 0; g < 4; ++g) {
        int c = wave * 16 + g * 4;
        float4 v = *(const float4*)&tile[lane * 68 + c];
        obase[(size_t)(c + 0) * NN] = v.x;
        obase[(size_t)(c + 1) * NN] = v.y;
        obase[(size_t)(c + 2) * NN] = v.z;
        obase[(size_t)(c + 3) * NN] = v.w;
    }
}

// ---------------------------------------------------------------------------
extern "C" void kernel_launch(void* const* d_in, const int* in_sizes, int n_in,
                              void* d_out, int out_size, void* d_ws, size_t ws_size,
                              hipStream_t stream) {
    const float* xyz1    = (const float*)d_in[0];   // [B,3,N]
    const float* xyz2    = (const float*)d_in[1];   // [B,3,S]
    const float* points2 = (const float*)d_in[2];   // [B,CIN,S]
    const float* W       = (const float*)d_in[3];   // [COUT,CIN]
    const float* bias    = (const float*)d_in[4];   // [COUT]
    float* out = (float*)d_out;                     // [B,COUT,N]

    char* ws = (char*)d_ws;
    // workspace layout (bytes), total ~16.8 MB:
    //   pk  : 0        ..  6,291,456  ([SC=4][B][3][N] u64 packed keys)
    //   Gh  : 6291456  .. 14,680,064  ([B][S][COUT] bf16)
    //   wi4 : 14680064 .. 15,728,640  ([B][N] float4)
    //   gi4 : 15728640 .. 16,777,216  ([B][N] int4)
    unsigned long long* pk  = (unsigned long long*)(ws);
    unsigned short*     Gh  = (unsigned short*)(ws + 6291456);
    float4*             wi4 = (float4*)(ws + 14680064);
    int4*               gi4 = (int4*)(ws + 15728640);

    k_fused<<<dim3(KNNB + GEMMB), 256, 0, stream>>>(xyz1, xyz2, points2, W, bias,
                                                    Gh, pk);
    k_merge<<<dim3(NN / 256, BB), 256, 0, stream>>>(pk, xyz1, wi4, gi4);
    k_out<<<dim3(4096), 256, 0, stream>>>(Gh, wi4, gi4, out);
}

// Round 3
// 265.784 us; speedup vs baseline: 1.0023x; 1.0023x over previous
//
#include <hip/hip_runtime.h>

#define BB 4
#define NN 16384
#define SS 4096
#define CIN 256
#define COUT 256

#define SC 8                  // s-chunks for knn
#define SCS (SS / SC)         // 512 points per chunk (8 KB LDS)
#define NPT 4                 // queries per thread in knn
#define QPB (256 * NPT)       // 1024 queries per knn block
#define KNNB ((NN / QPB) * SC * BB)           // 16*8*4 = 512 knn blocks
#define GEMMB ((COUT / 64) * (SS / 64) * BB)  // 4*64*4 = 1024 gemm blocks
// grid = 1536 = 6 blocks/CU, all co-resident at t=0; knn at bid%3==0
// interleaves the long knn blocks evenly across CUs/XCDs (gcd(8,3)=1).

typedef float v2f __attribute__((ext_vector_type(2)));
typedef float v4f __attribute__((ext_vector_type(4)));

__device__ __forceinline__ unsigned short f2bf(float f) {   // RNE float->bf16
    unsigned u = __float_as_uint(f);
    u += 0x7FFF + ((u >> 16) & 1);
    return (unsigned short)(u >> 16);
}
__device__ __forceinline__ float bf2f(unsigned short h) {
    return __uint_as_float((unsigned)h << 16);
}

// Exact stable top-3 insert, f32 values + explicit index tracking.
// Strict '<' + candidates processed in ascending global index == reference
// stable top_k tie-break (later equal value does NOT displace an earlier
// one, but does fill the next slot). All ops full-rate f32/int:
// 3 v_cmp + fminf + 2 v_med3_f32 + 5 v_cndmask = 11 slots per query.
__device__ __forceinline__ void insert_vi(float e, int gi,
                                          float& k0, float& k1, float& k2,
                                          int& i0, int& i1, int& i2) {
    bool c0 = e < k0, c1 = e < k1, c2 = e < k2;
    float n0 = fminf(e, k0);
    float n1 = __builtin_amdgcn_fmed3f(e, k0, k1);
    float n2 = __builtin_amdgcn_fmed3f(e, k1, k2);
    int t1 = c0 ? i0 : gi;
    int t2 = c1 ? i1 : gi;
    i0 = c0 ? gi : i0;
    i1 = c1 ? t1 : i1;
    i2 = c2 ? t2 : i2;
    k0 = n0; k1 = n1; k2 = n2;
}

// v_pk_fma_f32 packed distance: lo/hi = two queries; candidate coords
// broadcast via op_sel. IEEE f32 fma per half, z->y->x order.
#define E2_FROM(p_xy, p_zw, XX, YY, ZZ, e2)                                    \
    do {                                                                       \
        asm("v_pk_fma_f32 %0, %1, %2, %3 op_sel:[0,0,1] op_sel_hi:[0,1,1]"     \
            : "=v"(e2) : "v"(p_zw), "v"(ZZ), "v"(p_zw));                       \
        asm("v_pk_fma_f32 %0, %1, %2, %0 op_sel:[1,0,0] op_sel_hi:[1,1,1]"     \
            : "+v"(e2) : "v"(p_xy), "v"(YY));                                  \
        asm("v_pk_fma_f32 %0, %1, %2, %0 op_sel:[0,0,0] op_sel_hi:[0,1,1]"     \
            : "+v"(e2) : "v"(p_xy), "v"(XX));                                  \
    } while (0)

#define PK_LO(acc, ap, bw)                                                     \
    asm("v_pk_fma_f32 %0, %1, %2, %0 op_sel:[0,0,0] op_sel_hi:[0,1,1]"         \
        : "+v"(acc) : "v"(ap), "v"(bw))
#define PK_HI(acc, ap, bw)                                                     \
    asm("v_pk_fma_f32 %0, %1, %2, %0 op_sel:[1,0,0] op_sel_hi:[1,1,1]"         \
        : "+v"(acc) : "v"(ap), "v"(bw))

// ---------------------------------------------------------------------------
// knn phase, single pass, NPT=4: one ds_read_b128 per candidate serves 4
// queries (halves knn LDS issue vs NPT=2). Per candidate: 6 pk_fma +
// 4 x 11-slot exact insert. No f64, no branch, 4 independent dep chains.
// ---------------------------------------------------------------------------
__device__ __forceinline__ void knn_phase(int id, int t, float* smem,
                                          const float* __restrict__ xyz1,
                                          const float* __restrict__ xyz2,
                                          uint2* __restrict__ pk) {
    int nb = id & 15;
    int ch = (id >> 4) & 7;
    int b  = id >> 7;
    int s0 = ch * SCS;

    float4* smv = (float4*)smem;
    const float* x2 = xyz2 + (size_t)b * 3 * SS;
    for (int i = t; i < SCS; i += 256) {
        float px = x2[s0 + i];
        float py = x2[SS + s0 + i];
        float pz = x2[2 * SS + s0 + i];
        smv[i] = make_float4(px, py, pz, fmaf(px, px, fmaf(py, py, pz * pz)));
    }
    __syncthreads();

    int n0 = nb * QPB + t;             // queries n0 + {0,256,512,768}
    const float* xb = xyz1 + (size_t)b * 3 * NN;
    float qx[NPT], qy[NPT], qz[NPT];
#pragma unroll
    for (int q = 0; q < NPT; ++q) {
        qx[q] = xb[n0 + q * 256];
        qy[q] = xb[NN + n0 + q * 256];
        qz[q] = xb[2 * NN + n0 + q * 256];
    }
    v2f XXa = {-2.0f * qx[0], -2.0f * qx[1]};
    v2f YYa = {-2.0f * qy[0], -2.0f * qy[1]};
    v2f ZZa = {-2.0f * qz[0], -2.0f * qz[1]};
    v2f XXb = {-2.0f * qx[2], -2.0f * qx[3]};
    v2f YYb = {-2.0f * qy[2], -2.0f * qy[3]};
    v2f ZZb = {-2.0f * qz[2], -2.0f * qz[3]};

    float k0[NPT], k1[NPT], k2[NPT];
    int   i0[NPT], i1[NPT], i2[NPT];
#pragma unroll
    for (int q = 0; q < NPT; ++q) {
        k0[q] = 1e30f; k1[q] = 1e30f; k2[q] = 1e30f;
        i0[q] = 0;     i1[q] = 0;     i2[q] = 0;
    }

#pragma unroll 8
    for (int s = 0; s < SCS; ++s) {
        v4f p = *(const v4f*)(smem + 4 * s);
        v2f pxy = __builtin_shufflevector(p, p, 0, 1);
        v2f pzw = __builtin_shufflevector(p, p, 2, 3);
        v2f eA, eB;
        E2_FROM(pxy, pzw, XXa, YYa, ZZa, eA);
        E2_FROM(pxy, pzw, XXb, YYb, ZZb, eB);
        int gi = s0 + s;
        insert_vi(eA.x, gi, k0[0], k1[0], k2[0], i0[0], i1[0], i2[0]);
        insert_vi(eA.y, gi, k0[1], k1[1], k2[1], i0[1], i1[1], i2[1]);
        insert_vi(eB.x, gi, k0[2], k1[2], k2[2], i0[2], i1[2], i2[2]);
        insert_vi(eB.y, gi, k0[3], k1[3], k2[3], i0[3], i1[3], i2[3]);
    }

    // layout [ch][b][j][n], uint2 {value bits, index} (coalesced 8B/lane)
    size_t cb = (size_t)(ch * BB + b) * 3;
#pragma unroll
    for (int q = 0; q < NPT; ++q) {
        int n = n0 + q * 256;
        pk[(cb + 0) * NN + n] = make_uint2(__float_as_uint(k0[q]), (unsigned)i0[q]);
        pk[(cb + 1) * NN + n] = make_uint2(__float_as_uint(k1[q]), (unsigned)i1[q]);
        pk[(cb + 2) * NN + n] = make_uint2(__float_as_uint(k2[q]), (unsigned)i2[q]);
    }
}

// ---------------------------------------------------------------------------
// gemm phase: 64s x 64o tile, 4x4 micro via 8 v_pk_fma_f32 per cc (unchanged).
// ---------------------------------------------------------------------------
__device__ __forceinline__ void gemm_phase(int g, int t, float* smem,
                                           const float* __restrict__ P,
                                           const float* __restrict__ W,
                                           const float* __restrict__ bias,
                                           unsigned short* __restrict__ Gh) {
    int o0 = (g & 3) * 64;
    int s0 = ((g >> 2) & 63) * 64;
    int b  = g >> 8;
    float* sP = smem;              // 16 x 64
    float* sW = smem + 1024;       // 16 x 68 (padded)
    int i = t & 15;
    int j = t >> 4;

    v2f acc2[4][2];
#pragma unroll
    for (int p = 0; p < 4; ++p) {
        acc2[p][0] = (v2f){0.f, 0.f};
        acc2[p][1] = (v2f){0.f, 0.f};
    }

    const float* Pb = P + (size_t)b * CIN * SS;

    for (int c0 = 0; c0 < CIN; c0 += 16) {
        __syncthreads();
        {
            int col = t & 63;
            int r0r = t >> 6;
#pragma unroll
            for (int r = 0; r < 4; ++r) {
                int row = r0r + r * 4;
                sP[row * 64 + col] = Pb[(size_t)(c0 + row) * SS + s0 + col];
            }
        }
        {
            int cc = t & 15;
            int obase = t >> 4;
#pragma unroll
            for (int r = 0; r < 4; ++r) {
                int oo = obase + 16 * r;
                sW[cc * 68 + oo] = W[(size_t)(o0 + oo) * CIN + c0 + cc];
            }
        }
        __syncthreads();

#pragma unroll
        for (int cc = 0; cc < 16; ++cc) {
            v4f a  = *(const v4f*)&sP[cc * 64 + i * 4];
            v4f bv = *(const v4f*)&sW[cc * 68 + j * 4];
            v2f a01 = __builtin_shufflevector(a, a, 0, 1);
            v2f a23 = __builtin_shufflevector(a, a, 2, 3);
            v2f b01 = __builtin_shufflevector(bv, bv, 0, 1);
            v2f b23 = __builtin_shufflevector(bv, bv, 2, 3);
            PK_LO(acc2[0][0], a01, b01); PK_LO(acc2[0][1], a01, b23);  // a.x
            PK_HI(acc2[1][0], a01, b01); PK_HI(acc2[1][1], a01, b23);  // a.y
            PK_LO(acc2[2][0], a23, b01); PK_LO(acc2[2][1], a23, b23);  // a.z
            PK_HI(acc2[3][0], a23, b01); PK_HI(acc2[3][1], a23, b23);  // a.w
        }
    }

    float b0 = bias[o0 + j * 4 + 0];
    float b1 = bias[o0 + j * 4 + 1];
    float b2 = bias[o0 + j * 4 + 2];
    float b3 = bias[o0 + j * 4 + 3];
#pragma unroll
    for (int p = 0; p < 4; ++p) {
        ushort4 v;
        v.x = f2bf(acc2[p][0].x + b0);
        v.y = f2bf(acc2[p][0].y + b1);
        v.z = f2bf(acc2[p][1].x + b2);
        v.w = f2bf(acc2[p][1].y + b3);
        size_t off = ((size_t)b * SS + s0 + i * 4 + p) * COUT + o0 + j * 4;
        *(ushort4*)&Gh[off] = v;
    }
}

// ---------------------------------------------------------------------------
__global__ __launch_bounds__(256) void k_fused(const float* __restrict__ xyz1,
                                               const float* __restrict__ xyz2,
                                               const float* __restrict__ P,
                                               const float* __restrict__ W,
                                               const float* __restrict__ bias,
                                               unsigned short* __restrict__ Gh,
                                               uint2* __restrict__ pk) {
    __shared__ float smem[2112];   // 8.25 KB: knn 512 float4 / gemm sP+sW
    int bid = blockIdx.x;
    int t   = threadIdx.x;

    if (bid % 3 == 0) {
        knn_phase(bid / 3, t, smem, xyz1, xyz2, pk);
    } else {
        gemm_phase(bid - bid / 3 - 1, t, smem, P, W, bias, Gh);
    }
}

// ---------------------------------------------------------------------------
// Merge: fold SC*3 = 24 (value,index) pairs per query in ascending (ch, j)
// order (within-chunk slots value-sorted; cross-chunk equal-value order
// preserved by strict '<') -> exact stable top-3. Weights from exact f32 e.
// ---------------------------------------------------------------------------
__global__ __launch_bounds__(256) void k_merge(const uint2* __restrict__ pk,
                                               const float* __restrict__ xyz1,
                                               float4* __restrict__ wi4,
                                               int4* __restrict__ gi4) {
    int b = blockIdx.y;
    int n = blockIdx.x * 256 + threadIdx.x;

    float k0 = 1e30f, k1 = 1e30f, k2 = 1e30f;
    int   i0 = 0,     i1 = 0,     i2 = 0;
#pragma unroll
    for (int ch = 0; ch < SC; ++ch) {
        size_t cb = (size_t)(ch * BB + b) * 3;
#pragma unroll
        for (int j = 0; j < 3; ++j) {
            uint2 u = pk[(cb + j) * NN + n];
            insert_vi(__uint_as_float(u.x), (int)u.y, k0, k1, k2, i0, i1, i2);
        }
    }

    const float* xb = xyz1 + (size_t)b * 3 * NN;
    float qx = xb[n], qy = xb[NN + n], qz = xb[2 * NN + n];
    float n1 = fmaf(qx, qx, fmaf(qy, qy, qz * qz));

    float d0 = k0 + n1, d1 = k1 + n1, d2 = k2 + n1;
    float r0 = 1.0f / (d0 + 1e-8f);
    float r1 = 1.0f / (d1 + 1e-8f);
    float r2 = 1.0f / (d2 + 1e-8f);
    float inv = 1.0f / (r0 + r1 + r2);
    size_t q = (size_t)b * NN + n;
    wi4[q] = make_float4(r0 * inv, r1 * inv, r2 * inv, 0.f);
    gi4[q] = make_int4(i0, i1, i2, 0);
}

// ---------------------------------------------------------------------------
// Output: unchanged (XCD-swizzled flat grid, 64q x 64ch blocks,
// 4-query/wave MLP gather, stride-68 tile, coalesced stores).
// ---------------------------------------------------------------------------
__global__ __launch_bounds__(256) void k_out(const unsigned short* __restrict__ Gh,
                                             const float4* __restrict__ wi4,
                                             const int4* __restrict__ gi4,
                                             float* __restrict__ out) {
    __shared__ float  tile[64 * 68];   // 17.4 KB
    __shared__ float4 swv[64];
    __shared__ int4   siv[64];
    int bid  = blockIdx.x;
    int x    = bid & 7;                // XCD slot (blockIdx % 8 round-robin)
    int b    = x >> 1;                 // 2 XCDs per batch
    int local = (bid >> 3) + (x & 1) * 512;   // 0..1023 per batch
    int nb   = local & 255;            // 256 n-blocks
    int oc   = local >> 8;             // 4 o-chunks
    int n0   = nb * 64;
    int o0   = oc * 64;
    int t    = threadIdx.x;
    int wave = t >> 6;
    int lane = t & 63;
    int qg   = lane >> 4;     // query-in-group 0..3
    int c16  = lane & 15;     // channel quad 0..15

    if (t < 64) {
        size_t q = (size_t)b * NN + n0 + t;
        swv[t] = wi4[q];
        siv[t] = gi4[q];
    }
    __syncthreads();

    const unsigned short* Gb = Gh + (size_t)b * SS * COUT;

#pragma unroll
    for (int pass = 0; pass < 4; ++pass) {
        int q = pass * 16 + wave * 4 + qg;
        float4 wv = swv[q];
        int4   iv = siv[q];
        int co = o0 + c16 * 4;
        ushort4 a0 = *(const ushort4*)(Gb + (size_t)iv.x * COUT + co);
        ushort4 a1 = *(const ushort4*)(Gb + (size_t)iv.y * COUT + co);
        ushort4 a2 = *(const ushort4*)(Gb + (size_t)iv.z * COUT + co);
        float4 v;
        v.x = fmaf(wv.x, bf2f(a0.x), fmaf(wv.y, bf2f(a1.x), wv.z * bf2f(a2.x)));
        v.y = fmaf(wv.x, bf2f(a0.y), fmaf(wv.y, bf2f(a1.y), wv.z * bf2f(a2.y)));
        v.z = fmaf(wv.x, bf2f(a0.z), fmaf(wv.y, bf2f(a1.z), wv.z * bf2f(a2.z)));
        v.w = fmaf(wv.x, bf2f(a0.w), fmaf(wv.y, bf2f(a1.w), wv.z * bf2f(a2.w)));
        *(float4*)&tile[q * 68 + c16 * 4] = v;
    }
    __syncthreads();

    float* obase = out + ((size_t)b * COUT + o0) * NN + n0 + lane;
#pragma unroll
    for (int g = 0; g < 4; ++g) {
        int c = wave * 16 + g * 4;
        float4 v = *(const float4*)&tile[lane * 68 + c];
        obase[(size_t)(c + 0) * NN] = v.x;
        obase[(size_t)(c + 1) * NN] = v.y;
        obase[(size_t)(c + 2) * NN] = v.z;
        obase[(size_t)(c + 3) * NN] = v.w;
    }
}

// ---------------------------------------------------------------------------
extern "C" void kernel_launch(void* const* d_in, const int* in_sizes, int n_in,
                              void* d_out, int out_size, void* d_ws, size_t ws_size,
                              hipStream_t stream) {
    const float* xyz1    = (const float*)d_in[0];   // [B,3,N]
    const float* xyz2    = (const float*)d_in[1];   // [B,3,S]
    const float* points2 = (const float*)d_in[2];   // [B,CIN,S]
    const float* W       = (const float*)d_in[3];   // [COUT,CIN]
    const float* bias    = (const float*)d_in[4];   // [COUT]
    float* out = (float*)d_out;                     // [B,COUT,N]

    char* ws = (char*)d_ws;
    // workspace layout (bytes), total ~23 MB:
    //   pk  : 0        .. 12,582,912  ([SC=8][B][3][N] uint2 {val,idx})
    //   Gh  : 12582912 .. 20,971,520  ([B][S][COUT] bf16)
    //   wi4 : 20971520 .. 22,020,096  ([B][N] float4)
    //   gi4 : 22020096 .. 23,068,672  ([B][N] int4)
    uint2*          pk  = (uint2*)(ws);
    unsigned short* Gh  = (unsigned short*)(ws + 12582912);
    float4*         wi4 = (float4*)(ws + 20971520);
    int4*           gi4 = (int4*)(ws + 22020096);

    k_fused<<<dim3(KNNB + GEMMB), 256, 0, stream>>>(xyz1, xyz2, points2, W, bias,
                                                    Gh, pk);
    k_merge<<<dim3(NN / 256, BB), 256, 0, stream>>>(pk, xyz1, wi4, gi4);
    k_out<<<dim3(4096), 256, 0, stream>>>(Gh, wi4, gi4, out);
}

// Round 5
// 218.905 us; speedup vs baseline: 1.2169x; 1.2142x over previous
//
#include <hip/hip_runtime.h>

#define BB 4
#define NN 16384
#define SS 4096
#define CIN 256
#define COUT 256

#define SC 8                  // s-chunks per knn block pass
#define SCS (SS / SC)         // 512 candidates staged per knn block
#define SUBS 16               // value-dump granularity: 16 subs of 256
#define SUBL 256
#define KNNB ((NN / 512) * SC * BB)           // 32*8*4 = 1024 knn blocks (NPT=2)
#define GEMMB ((COUT / 64) * (SS / 64) * BB)  // 4*64*4 = 1024 gemm blocks
// grid = 2048 = 8 blocks/CU (round-0 proven: 87% VALUBusy, no tail issues)

typedef float v2f __attribute__((ext_vector_type(2)));
typedef float v4f __attribute__((ext_vector_type(4)));

__device__ __forceinline__ unsigned short f2bf(float f) {   // RNE float->bf16
    unsigned u = __float_as_uint(f);
    u += 0x7FFF + ((u >> 16) & 1);
    return (unsigned short)(u >> 16);
}
__device__ __forceinline__ float bf2f(unsigned short h) {
    return __uint_as_float((unsigned)h << 16);
}

// Exact stable top-3 insert, f32 values + explicit index tracking (used ONLY
// in k_resolve over <=3*256 candidates/query). Strict '<' + ascending global
// index processing == reference stable top_k tie-break.
__device__ __forceinline__ void insert_vi(float e, int gi,
                                          float& k0, float& k1, float& k2,
                                          int& i0, int& i1, int& i2) {
    bool c0 = e < k0, c1 = e < k1, c2 = e < k2;
    float n0 = fminf(e, k0);
    float n1 = __builtin_amdgcn_fmed3f(e, k0, k1);
    float n2 = __builtin_amdgcn_fmed3f(e, k1, k2);
    int t1 = c0 ? i0 : gi;
    int t2 = c1 ? i1 : gi;
    i0 = c0 ? gi : i0;
    i1 = c1 ? t1 : i1;
    i2 = c2 ? t2 : i2;
    k0 = n0; k1 = n1; k2 = n2;
}

// v_pk_fma_f32 packed distance: lo/hi = two queries; candidate coords
// broadcast via op_sel. IEEE f32 fma per half, z->y->x nesting:
//   e = x*X + (y*Y + (z*Z + w))
#define E2_FROM(p_xy, p_zw, XX, YY, ZZ, e2)                                    \
    do {                                                                       \
        asm("v_pk_fma_f32 %0, %1, %2, %3 op_sel:[0,0,1] op_sel_hi:[0,1,1]"     \
            : "=v"(e2) : "v"(p_zw), "v"(ZZ), "v"(p_zw));                       \
        asm("v_pk_fma_f32 %0, %1, %2, %0 op_sel:[1,0,0] op_sel_hi:[1,1,1]"     \
            : "+v"(e2) : "v"(p_xy), "v"(YY));                                  \
        asm("v_pk_fma_f32 %0, %1, %2, %0 op_sel:[0,0,0] op_sel_hi:[0,1,1]"     \
            : "+v"(e2) : "v"(p_xy), "v"(XX));                                  \
    } while (0)

#define PK_LO(acc, ap, bw)                                                     \
    asm("v_pk_fma_f32 %0, %1, %2, %0 op_sel:[0,0,0] op_sel_hi:[0,1,1]"         \
        : "+v"(acc) : "v"(ap), "v"(bw))
#define PK_HI(acc, ap, bw)                                                     \
    asm("v_pk_fma_f32 %0, %1, %2, %0 op_sel:[1,0,0] op_sel_hi:[1,1,1]"         \
        : "+v"(acc) : "v"(ap), "v"(bw))

// ---------------------------------------------------------------------------
// knn phase (NPT=2): VALUE-ONLY exact top-3 per 256-candidate sub-chunk.
// Per candidate-iter: 1 ds_read_b128 + 3 pk_fma + 2x(fminf + 2 v_med3_f32).
// No index tracking, no f64, no compares. Sorted invariant k0<=k1<=k2:
//   n1 = med3(e,k0,k1), n2 = med3(e,k1,k2), k0 = min(e,k0)  (exact).
// Dump [sub][b][j][n] f32, coalesced 4B stores.
// ---------------------------------------------------------------------------
__device__ __forceinline__ void knn_phase(int id, int t, float* smem,
                                          const float* __restrict__ xyz1,
                                          const float* __restrict__ xyz2,
                                          float* __restrict__ pv) {
    int nb = id & 31;
    int ch = (id >> 5) & 7;
    int b  = id >> 8;
    int s0 = ch * SCS;

    float4* smv = (float4*)smem;
    const float* x2 = xyz2 + (size_t)b * 3 * SS;
    for (int i = t; i < SCS; i += 256) {
        float px = x2[s0 + i];
        float py = x2[SS + s0 + i];
        float pz = x2[2 * SS + s0 + i];
        smv[i] = make_float4(px, py, pz, fmaf(px, px, fmaf(py, py, pz * pz)));
    }
    __syncthreads();

    int n0  = nb * 512 + t;
    int n1q = n0 + 256;
    const float* xb = xyz1 + (size_t)b * 3 * NN;
    float ax = xb[n0],  ay = xb[NN + n0],  az = xb[2 * NN + n0];
    float bx = xb[n1q], by = xb[NN + n1q], bz = xb[2 * NN + n1q];
    v2f XX = {-2.0f * ax, -2.0f * bx};
    v2f YY = {-2.0f * ay, -2.0f * by};
    v2f ZZ = {-2.0f * az, -2.0f * bz};

#pragma unroll
    for (int half = 0; half < 2; ++half) {
        float A0 = 1e30f, A1 = 1e30f, A2 = 1e30f;
        float B0 = 1e30f, B1 = 1e30f, B2 = 1e30f;
        int sb = half * SUBL;
#pragma unroll 8
        for (int s = sb; s < sb + SUBL; ++s) {
            v4f p = *(const v4f*)(smem + 4 * s);
            v2f pxy = __builtin_shufflevector(p, p, 0, 1);
            v2f pzw = __builtin_shufflevector(p, p, 2, 3);
            v2f e2;
            E2_FROM(pxy, pzw, XX, YY, ZZ, e2);
            float nA1 = __builtin_amdgcn_fmed3f(e2.x, A0, A1);
            float nA2 = __builtin_amdgcn_fmed3f(e2.x, A1, A2);
            A0 = fminf(A0, e2.x); A1 = nA1; A2 = nA2;
            float nB1 = __builtin_amdgcn_fmed3f(e2.y, B0, B1);
            float nB2 = __builtin_amdgcn_fmed3f(e2.y, B1, B2);
            B0 = fminf(B0, e2.y); B1 = nB1; B2 = nB2;
        }
        int sub = ch * 2 + half;
        size_t base = (size_t)(sub * BB + b) * 3;
        pv[(base + 0) * NN + n0]  = A0;
        pv[(base + 1) * NN + n0]  = A1;
        pv[(base + 2) * NN + n0]  = A2;
        pv[(base + 0) * NN + n1q] = B0;
        pv[(base + 1) * NN + n1q] = B1;
        pv[(base + 2) * NN + n1q] = B2;
    }
}

// ---------------------------------------------------------------------------
// gemm phase: 64s x 64o tile, 4x4 micro via 8 v_pk_fma_f32 per cc (unchanged,
// passing since round 1).
// ---------------------------------------------------------------------------
__device__ __forceinline__ void gemm_phase(int g, int t, float* smem,
                                           const float* __restrict__ P,
                                           const float* __restrict__ W,
                                           const float* __restrict__ bias,
                                           unsigned short* __restrict__ Gh) {
    int o0 = (g & 3) * 64;
    int s0 = ((g >> 2) & 63) * 64;
    int b  = g >> 8;
    float* sP = smem;              // 16 x 64
    float* sW = smem + 1024;       // 16 x 68 (padded)
    int i = t & 15;
    int j = t >> 4;

    v2f acc2[4][2];
#pragma unroll
    for (int p = 0; p < 4; ++p) {
        acc2[p][0] = (v2f){0.f, 0.f};
        acc2[p][1] = (v2f){0.f, 0.f};
    }

    const float* Pb = P + (size_t)b * CIN * SS;

    for (int c0 = 0; c0 < CIN; c0 += 16) {
        __syncthreads();
        {
            int col = t & 63;
            int r0r = t >> 6;
#pragma unroll
            for (int r = 0; r < 4; ++r) {
                int row = r0r + r * 4;
                sP[row * 64 + col] = Pb[(size_t)(c0 + row) * SS + s0 + col];
            }
        }
        {
            int cc = t & 15;
            int obase = t >> 4;
#pragma unroll
            for (int r = 0; r < 4; ++r) {
                int oo = obase + 16 * r;
                sW[cc * 68 + oo] = W[(size_t)(o0 + oo) * CIN + c0 + cc];
            }
        }
        __syncthreads();

#pragma unroll
        for (int cc = 0; cc < 16; ++cc) {
            v4f a  = *(const v4f*)&sP[cc * 64 + i * 4];
            v4f bv = *(const v4f*)&sW[cc * 68 + j * 4];
            v2f a01 = __builtin_shufflevector(a, a, 0, 1);
            v2f a23 = __builtin_shufflevector(a, a, 2, 3);
            v2f b01 = __builtin_shufflevector(bv, bv, 0, 1);
            v2f b23 = __builtin_shufflevector(bv, bv, 2, 3);
            PK_LO(acc2[0][0], a01, b01); PK_LO(acc2[0][1], a01, b23);  // a.x
            PK_HI(acc2[1][0], a01, b01); PK_HI(acc2[1][1], a01, b23);  // a.y
            PK_LO(acc2[2][0], a23, b01); PK_LO(acc2[2][1], a23, b23);  // a.z
            PK_HI(acc2[3][0], a23, b01); PK_HI(acc2[3][1], a23, b23);  // a.w
        }
    }

    float b0 = bias[o0 + j * 4 + 0];
    float b1 = bias[o0 + j * 4 + 1];
    float b2 = bias[o0 + j * 4 + 2];
    float b3 = bias[o0 + j * 4 + 3];
#pragma unroll
    for (int p = 0; p < 4; ++p) {
        ushort4 v;
        v.x = f2bf(acc2[p][0].x + b0);
        v.y = f2bf(acc2[p][0].y + b1);
        v.z = f2bf(acc2[p][1].x + b2);
        v.w = f2bf(acc2[p][1].y + b3);
        size_t off = ((size_t)b * SS + s0 + i * 4 + p) * COUT + o0 + j * 4;
        *(ushort4*)&Gh[off] = v;
    }
}

// ---------------------------------------------------------------------------
// Fused kernel, round-0 proven split: blocks [0,KNNB)=knn, rest=gemm.
// ---------------------------------------------------------------------------
__global__ __launch_bounds__(256) void k_fused(const float* __restrict__ xyz1,
                                               const float* __restrict__ xyz2,
                                               const float* __restrict__ P,
                                               const float* __restrict__ W,
                                               const float* __restrict__ bias,
                                               unsigned short* __restrict__ Gh,
                                               float* __restrict__ pv) {
    __shared__ float smem[2112];   // 8.25 KB: knn 512 float4 / gemm sP+sW
    int bid = blockIdx.x;
    int t   = threadIdx.x;

    if (bid < KNNB) {
        knn_phase(bid, t, smem, xyz1, xyz2, pv);
    } else {
        gemm_phase(bid - KNNB, t, smem, P, W, bias, Gh);
    }
}

// ---------------------------------------------------------------------------
// Resolve: fold 16x3 values -> v0<=v1<=v2 (global top-3 values, exact);
// winning subs = {sub : sub_min <= v2} (<=3 generically, +1 tie slot,
// overflow path scans all). Re-scan only winning subs from a full-S LDS
// copy (XOR-swizzled: divergent-sub reads <=2-way bank alias), recomputing
// e BITWISE identically to knn (same fma nesting), exact stable insert_vi
// in ascending global s. Weights from exact scan values.
// ---------------------------------------------------------------------------
__global__ __launch_bounds__(256) void k_resolve(const float* __restrict__ pv,
                                                 const float* __restrict__ xyz1,
                                                 const float* __restrict__ xyz2,
                                                 float4* __restrict__ wi4,
                                                 int4* __restrict__ gi4) {
    __shared__ float4 cand[4096];   // 64 KB, idx = sub*256 + (s ^ (sub&7))
    int b    = blockIdx.x >> 6;
    int nblk = blockIdx.x & 63;
    int t    = threadIdx.x;

    const float* x2 = xyz2 + (size_t)b * 3 * SS;
    for (int i = t; i < SS; i += 256) {
        int sub = i >> 8, s = i & 255;
        float px = x2[i];
        float py = x2[SS + i];
        float pz = x2[2 * SS + i];
        cand[sub * SUBL + (s ^ (sub & 7))] =
            make_float4(px, py, pz, fmaf(px, px, fmaf(py, py, pz * pz)));
    }
    __syncthreads();

    int n = nblk * 256 + t;

    // fold 48 per-sub values -> global top-3 values (multiset, order-free)
    float v0 = 1e30f, v1 = 1e30f, v2v = 1e30f;
#pragma unroll 4
    for (int sub = 0; sub < SUBS; ++sub) {
        size_t base = (size_t)(sub * BB + b) * 3;
#pragma unroll
        for (int j = 0; j < 3; ++j) {
            float a  = pv[(base + j) * NN + n];
            float t1 = __builtin_amdgcn_fmed3f(a, v0, v1);
            float t2 = __builtin_amdgcn_fmed3f(a, v1, v2v);
            v0 = fminf(v0, a); v1 = t1; v2v = t2;
        }
    }

    // winning-sub list (ascending sub order)
    int l0 = 0, l1 = 0, l2 = 0, l3 = 0, cnt = 0;
#pragma unroll 4
    for (int sub = 0; sub < SUBS; ++sub) {
        float a0 = pv[(size_t)(sub * BB + b) * 3 * NN + n];
        if (a0 <= v2v) {
            if      (cnt == 0) l0 = sub;
            else if (cnt == 1) l1 = sub;
            else if (cnt == 2) l2 = sub;
            else if (cnt == 3) l3 = sub;
            ++cnt;
        }
    }

    const float* xb = xyz1 + (size_t)b * 3 * NN;
    float qx = xb[n], qy = xb[NN + n], qz = xb[2 * NN + n];
    float xm2 = -2.0f * qx, ym2 = -2.0f * qy, zm2 = -2.0f * qz;
    float nrm = fmaf(qx, qx, fmaf(qy, qy, qz * qz));

    float k0 = 1e30f, k1 = 1e30f, k2 = 1e30f;
    int   i0 = 0,     i1 = 0,     i2 = 0;
    bool ovf  = (cnt > 4);          // exact-tie pathology: scan everything
    int  kmax = ovf ? SUBS : cnt;
    for (int k = 0; k < kmax; ++k) {
        int sub = ovf ? k : (k == 0 ? l0 : (k == 1 ? l1 : (k == 2 ? l2 : l3)));
        int xr = sub & 7;
        int sb = sub * SUBL;
#pragma unroll 8
        for (int s = 0; s < SUBL; ++s) {
            float4 p = cand[sb + (s ^ xr)];
            float e = fmaf(p.x, xm2, fmaf(p.y, ym2, fmaf(p.z, zm2, p.w)));
            insert_vi(e, sb + s, k0, k1, k2, i0, i1, i2);
        }
    }

    float d0 = k0 + nrm, d1 = k1 + nrm, d2 = k2 + nrm;
    float r0 = 1.0f / (d0 + 1e-8f);
    float r1 = 1.0f / (d1 + 1e-8f);
    float r2 = 1.0f / (d2 + 1e-8f);
    float inv = 1.0f / (r0 + r1 + r2);
    size_t q = (size_t)b * NN + n;
    wi4[q] = make_float4(r0 * inv, r1 * inv, r2 * inv, 0.f);
    gi4[q] = make_int4(i0, i1, i2, 0);
}

// ---------------------------------------------------------------------------
// Output: unchanged (XCD-swizzled flat grid, 64q x 64ch blocks,
// 4-query/wave MLP gather, stride-68 tile, coalesced stores).
// ---------------------------------------------------------------------------
__global__ __launch_bounds__(256) void k_out(const unsigned short* __restrict__ Gh,
                                             const float4* __restrict__ wi4,
                                             const int4* __restrict__ gi4,
                                             float* __restrict__ out) {
    __shared__ float  tile[64 * 68];   // 17.4 KB
    __shared__ float4 swv[64];
    __shared__ int4   siv[64];
    int bid  = blockIdx.x;
    int x    = bid & 7;                // XCD slot (blockIdx % 8 round-robin)
    int b    = x >> 1;                 // 2 XCDs per batch
    int local = (bid >> 3) + (x & 1) * 512;   // 0..1023 per batch
    int nb   = local & 255;            // 256 n-blocks
    int oc   = local >> 8;             // 4 o-chunks
    int n0   = nb * 64;
    int o0   = oc * 64;
    int t    = threadIdx.x;
    int wave = t >> 6;
    int lane = t & 63;
    int qg   = lane >> 4;     // query-in-group 0..3
    int c16  = lane & 15;     // channel quad 0..15

    if (t < 64) {
        size_t q = (size_t)b * NN + n0 + t;
        swv[t] = wi4[q];
        siv[t] = gi4[q];
    }
    __syncthreads();

    const unsigned short* Gb = Gh + (size_t)b * SS * COUT;

#pragma unroll
    for (int pass = 0; pass < 4; ++pass) {
        int q = pass * 16 + wave * 4 + qg;
        float4 wv = swv[q];
        int4   iv = siv[q];
        int co = o0 + c16 * 4;
        ushort4 a0 = *(const ushort4*)(Gb + (size_t)iv.x * COUT + co);
        ushort4 a1 = *(const ushort4*)(Gb + (size_t)iv.y * COUT + co);
        ushort4 a2 = *(const ushort4*)(Gb + (size_t)iv.z * COUT + co);
        float4 v;
        v.x = fmaf(wv.x, bf2f(a0.x), fmaf(wv.y, bf2f(a1.x), wv.z * bf2f(a2.x)));
        v.y = fmaf(wv.x, bf2f(a0.y), fmaf(wv.y, bf2f(a1.y), wv.z * bf2f(a2.y)));
        v.z = fmaf(wv.x, bf2f(a0.z), fmaf(wv.y, bf2f(a1.z), wv.z * bf2f(a2.z)));
        v.w = fmaf(wv.x, bf2f(a0.w), fmaf(wv.y, bf2f(a1.w), wv.z * bf2f(a2.w)));
        *(float4*)&tile[q * 68 + c16 * 4] = v;
    }
    __syncthreads();

    float* obase = out + ((size_t)b * COUT + o0) * NN + n0 + lane;
#pragma unroll
    for (int g = 0; g < 4; ++g) {
        int c = wave * 16 + g * 4;
        float4 v = *(const float4*)&tile[lane * 68 + c];
        obase[(size_t)(c + 0) * NN] = v.x;
        obase[(size_t)(c + 1) * NN] = v.y;
        obase[(size_t)(c + 2) * NN] = v.z;
        obase[(size_t)(c + 3) * NN] = v.w;
    }
}

// ---------------------------------------------------------------------------
extern "C" void kernel_launch(void* const* d_in, const int* in_sizes, int n_in,
                              void* d_out, int out_size, void* d_ws, size_t ws_size,
                              hipStream_t stream) {
    const float* xyz1    = (const float*)d_in[0];   // [B,3,N]
    const float* xyz2    = (const float*)d_in[1];   // [B,3,S]
    const float* points2 = (const float*)d_in[2];   // [B,CIN,S]
    const float* W       = (const float*)d_in[3];   // [COUT,CIN]
    const float* bias    = (const float*)d_in[4];   // [COUT]
    float* out = (float*)d_out;                     // [B,COUT,N]

    char* ws = (char*)d_ws;
    // workspace layout (bytes), total ~23 MB (identical to proven layout):
    //   pv  : 0        .. 12,582,912  ([SUBS=16][B][3][N] f32 sub top-3 values)
    //   Gh  : 12582912 .. 20,971,520  ([B][S][COUT] bf16)
    //   wi4 : 20971520 .. 22,020,096  ([B][N] float4)
    //   gi4 : 22020096 .. 23,068,672  ([B][N] int4)
    float*          pv  = (float*)(ws);
    unsigned short* Gh  = (unsigned short*)(ws + 12582912);
    float4*         wi4 = (float4*)(ws + 20971520);
    int4*           gi4 = (int4*)(ws + 22020096);

    k_fused<<<dim3(KNNB + GEMMB), 256, 0, stream>>>(xyz1, xyz2, points2, W, bias,
                                                    Gh, pv);
    k_resolve<<<dim3(256), 256, 0, stream>>>(pv, xyz1, xyz2, wi4, gi4);
    k_out<<<dim3(4096), 256, 0, stream>>>(Gh, wi4, gi4, out);
}